// Round 9
// baseline (861.689 us; speedup 1.0000x reference)
//
#include <hip/hip_runtime.h>
#include <cstdint>
#include <cstddef>

#define N_NODES   100000
#define M_PAD     100096   // 782 * 128
#define DIM       256
#define NTYPES    6
#define M_EDGES   400000
#define TOTAL_E   2400000
#define QUART_E   600000
#define NCOPY     8
#define NSCAN     800000   // NCOPY * N_NODES, copy-major: lin = c*N_NODES + tgt
#define SCAN_BLKS 782      // ceil(NSCAN/1024)

typedef _Float16 f16x8 __attribute__((ext_vector_type(8)));
typedef _Float16 f16x2 __attribute__((ext_vector_type(2)));
typedef float    f32x4 __attribute__((ext_vector_type(4)));

// ---- B16 = fp16(W)  (1536 x 256) ------------------------------------------
__global__ void build_b16(const float* __restrict__ W, _Float16* __restrict__ Bp){
    int tid = blockIdx.x * 256 + threadIdx.x;   // 1536*256/8 threads exact
    int idx = tid << 3;
    const f32x4* pw = (const f32x4*)(W + idx);
    f32x4 v0 = __builtin_nontemporal_load(pw);
    f32x4 v1 = __builtin_nontemporal_load(pw + 1);
    f16x8 h;
    h[0] = (_Float16)v0[0]; h[1] = (_Float16)v0[1]; h[2] = (_Float16)v0[2]; h[3] = (_Float16)v0[3];
    h[4] = (_Float16)v1[0]; h[5] = (_Float16)v1[1]; h[6] = (_Float16)v1[2]; h[7] = (_Float16)v1[3];
    *(f16x8*)(Bp + idx) = h;
}

// ---- gating table 2*sigmoid(posemb @ Wp^T + bp), fp64 trig, fp16 out ------
__global__ void build_gating(const float* __restrict__ Wp, const float* __restrict__ bp,
                             _Float16* __restrict__ gate){
    __shared__ float semb[256];
    int p = blockIdx.x;     // 0..511
    int t = threadIdx.x;    // 0..255
    if (t < 127){
        double invf = exp(-log(10000.0) * (2.0 * t) / 254.0);
        double a = (double)p * invf;
        semb[t]       = (float)sin(a);
        semb[t + 127] = (float)cos(a);
    } else if (t >= 254){
        semb[t] = 0.0f;
    }
    __syncthreads();
    float z = bp[t];
    const float* wr = Wp + (size_t)t * 256;
    #pragma unroll 4
    for (int kq = 0; kq < 256; ++kq) z += semb[kq] * wr[kq];
    gate[(size_t)p * 256 + t] = (_Float16)(2.0f / (1.0f + expf(-z)));
}

// ---- CSR over tgt, 8 XCD-private copies, single reused buffer -------------
// buf: cnt -> (scan) start offsets -> (scatter) END offsets.
__global__ void hist_kernel(const int* __restrict__ edges, int* __restrict__ buf){
    int t0 = blockIdx.x * 256 + threadIdx.x;
    if (t0 >= QUART_E) return;
    int copy = blockIdx.x & 7;
    #pragma unroll
    for (int j = 0; j < 4; ++j){
        int e = t0 + j * QUART_E;
        int tgt = edges[(size_t)e * 2 + 1];
        atomicAdd(buf + copy * N_NODES + tgt, 1);
    }
}

__global__ void scan1_kernel(int* __restrict__ buf, int* __restrict__ bsum){
    __shared__ int lds[256];
    int t = threadIdx.x;
    int base = blockIdx.x * 1024 + t * 4;
    int v[4]; int s = 0;
    #pragma unroll
    for (int j = 0; j < 4; ++j){
        int i = base + j;
        int val = (i < NSCAN) ? buf[i] : 0;
        v[j] = val; s += val;
    }
    lds[t] = s; __syncthreads();
    for (int d = 1; d < 256; d <<= 1){
        int xv = (t >= d) ? lds[t - d] : 0;
        __syncthreads();
        lds[t] += xv;
        __syncthreads();
    }
    int run = (t > 0) ? lds[t - 1] : 0;
    #pragma unroll
    for (int j = 0; j < 4; ++j){ int i = base + j; if (i < NSCAN) buf[i] = run; run += v[j]; }
    if (t == 255) bsum[blockIdx.x] = run;
}

__global__ void scan2_kernel(const int* __restrict__ bsum, int* __restrict__ ssum){
    __shared__ int lds[256];
    __shared__ int carry;
    int t = threadIdx.x;
    if (t == 0) carry = 0;
    __syncthreads();
    for (int ch = 0; ch < 4; ++ch){
        int idx = ch * 256 + t;
        int v = (idx < SCAN_BLKS) ? bsum[idx] : 0;
        lds[t] = v; __syncthreads();
        for (int d = 1; d < 256; d <<= 1){
            int xv = (t >= d) ? lds[t - d] : 0;
            __syncthreads();
            lds[t] += xv;
            __syncthreads();
        }
        int ex = carry + ((t > 0) ? lds[t - 1] : 0);
        if (idx < SCAN_BLKS) ssum[idx] = ex;
        __syncthreads();
        if (t == 255) carry += lds[255];
        __syncthreads();
    }
}

__global__ void scan3_kernel(int* __restrict__ buf, const int* __restrict__ ssum){
    int i = blockIdx.x * 256 + threadIdx.x;   // NSCAN exact (3125*256)
    buf[i] += ssum[i >> 10];
}

__global__ void scatter_kernel(const int* __restrict__ edges, const int* __restrict__ posl,
                               int* __restrict__ buf, unsigned* __restrict__ packed){
    int t0 = blockIdx.x * 256 + threadIdx.x;
    if (t0 >= QUART_E) return;
    int copy = blockIdx.x & 7;
    #pragma unroll
    for (int j = 0; j < 4; ++j){
        int e = t0 + j * QUART_E;
        int type = e / M_EDGES;
        int2 ed = *(const int2*)(edges + (size_t)e * 2);
        int p = atomicAdd(buf + copy * N_NODES + ed.y, 1);
        packed[p] = (unsigned)ed.x | ((unsigned)posl[e] << 17) | ((unsigned)type << 26);
    }
}

// ---- fp16 NT GEMM trio: propD[dh][tyBase+t] = f16(x) * B_t^T + b_t --------
// A: reg-staged from fp32 x with on-the-fly cvt (same LDS image as before).
// B: global_load_lds width-16, pre-swizzled source.
// Epilogue: per-wave LDS staging, f16x8 stores into dim-blocked prop layout.
__global__ __launch_bounds__(512, 4) void gemm_f16(
        const float* __restrict__ x,
        const _Float16* __restrict__ Bbase,
        const float* __restrict__ bbase,
        _Float16* __restrict__ propD,
        int tyBase)
{
    __shared__ __align__(16) char smem[49152];
    _Float16* sA = (_Float16*)smem;                 // 128*64 fp16 = 16 KB
    _Float16* sB = (_Float16*)(smem + 16384);       // 256*64 fp16 = 32 KB
    const int bid  = blockIdx.x;
    const int rp   = bid / 3;
    const int t    = bid - rp * 3;
    const int tid  = threadIdx.x;
    const int lane = tid & 63;
    const int wid  = tid >> 6;
    const int wr   = wid >> 2;   // 0..1
    const int wc   = wid & 3;    // 0..3
    const size_t m0 = (size_t)rp * 128;
    const _Float16* Bt = Bbase + (size_t)t * 256 * 256;

    f32x4 acc[4][4];
    #pragma unroll
    for (int m = 0; m < 4; ++m)
        #pragma unroll
        for (int n = 0; n < 4; ++n)
            acc[m][n] = (f32x4){0.f, 0.f, 0.f, 0.f};

    const int sub = lane >> 3;          // row within 8-row chunk (== r & 7)
    const int bib = (lane & 7) << 4;    // byte within 128B fp16-image row
    const int soff = bib ^ (sub << 4);  // pre-swizzled source byte offset (B)

    for (int kk = 0; kk < 4; ++kk){
        #pragma unroll
        for (int ci = 0; ci < 6; ++ci){
            int c = wid * 6 + ci;
            if (c < 16){
                // A: reg-stage fp32 -> fp16, swizzled LDS write
                int r = (c << 3) + sub;
                size_t grow = m0 + (size_t)r;
                f32x4 u0 = (f32x4){0.f,0.f,0.f,0.f};
                f32x4 u1 = (f32x4){0.f,0.f,0.f,0.f};
                if (grow < N_NODES){
                    const float* px = x + grow * 256 + (kk << 6) + ((lane & 7) << 3);
                    u0 = *(const f32x4*)px;
                    u1 = *(const f32x4*)(px + 4);
                }
                f16x8 hv;
                hv[0]=(_Float16)u0[0]; hv[1]=(_Float16)u0[1];
                hv[2]=(_Float16)u0[2]; hv[3]=(_Float16)u0[3];
                hv[4]=(_Float16)u1[0]; hv[5]=(_Float16)u1[1];
                hv[6]=(_Float16)u1[2]; hv[7]=(_Float16)u1[3];
                *(f16x8*)((char*)sA + r * 128 + (bib ^ (sub << 4))) = hv;
            } else {
                int c2 = c - 16;
                const char* gsrc = (const char*)(Bt + ((size_t)(c2 << 3) + sub) * 256);
                char* ldst = (char*)smem + 16384 + (c2 << 10);
                __builtin_amdgcn_global_load_lds(
                    (const __attribute__((address_space(1))) void*)(gsrc + (kk << 7) + soff),
                    (__attribute__((address_space(3))) void*)ldst, 16, 0, 0);
            }
        }
        __syncthreads();

        #pragma unroll
        for (int ks = 0; ks < 2; ++ks){
            int slot = (ks << 6) + ((lane >> 4) << 4);
            f16x8 af[4];
            #pragma unroll
            for (int m = 0; m < 4; ++m){
                int rA = (wr << 6) + (m << 4) + (lane & 15);
                af[m] = *(const f16x8*)((const char*)sA + rA * 128 + (slot ^ ((rA & 7) << 4)));
            }
            #pragma unroll
            for (int n = 0; n < 4; ++n){
                int rB = (wc << 6) + (n << 4) + (lane & 15);
                f16x8 bfr = *(const f16x8*)((const char*)sB + rB * 128 + (slot ^ ((rB & 7) << 4)));
                #pragma unroll
                for (int m = 0; m < 4; ++m)
                    acc[m][n] = __builtin_amdgcn_mfma_f32_16x16x32_f16(af[m], bfr, acc[m][n], 0, 0, 0);
            }
        }
        __syncthreads();
    }

    // ---- coalesced epilogue into dim-blocked prop: [dh][ty6][row][128] ----
    char* stage = smem + wid * 4096;
    float bv[4];
    #pragma unroll
    for (int n = 0; n < 4; ++n)
        bv[n] = bbase[(size_t)t * 256 + (wc << 6) + (n << 4) + (lane & 15)];

    #pragma unroll
    for (int ph = 0; ph < 2; ++ph){
        #pragma unroll
        for (int m2 = 0; m2 < 2; ++m2){
            int m = (ph << 1) + m2;
            #pragma unroll
            for (int n = 0; n < 4; ++n){
                #pragma unroll
                for (int j = 0; j < 4; ++j){
                    int lrow  = (m2 << 4) + ((lane >> 4) << 2) + j;
                    int lcolb = ((((n << 4) + (lane & 15)) << 1)) ^ (((lrow >> 2) & 3) << 5);
                    *(_Float16*)(stage + lrow * 128 + lcolb) =
                        (_Float16)(acc[m][n][j] + bv[n]);
                }
            }
        }
        #pragma unroll
        for (int r8 = 0; r8 < 4; ++r8){
            int lrow  = (r8 << 3) + (lane >> 3);
            int lcolb = (((lane & 7) << 4)) ^ (((lrow >> 2) & 3) << 5);
            f16x8 v = *(const f16x8*)(stage + lrow * 128 + lcolb);
            int grow = (int)m0 + (wr << 6) + (ph << 5) + lrow;
            int gcol = (wc << 6) + ((lane & 7) << 3);
            int cb   = gcol >> 7;
            int c128 = gcol & 127;
            _Float16* dst = propD + ((size_t)(cb * NTYPES + tyBase + t) * M_PAD
                                     + (size_t)grow) * 128 + c128;
            *(f16x8*)dst = v;
        }
    }
}

// ---- dim-half aggregation: ALL 6 types, L3-resident prop-half -------------
// one wave per tgt; out written once with divide fused (no RMW).
// endoff = buf after scatter (end offsets); start(lin) = lin ? endoff[lin-1] : 0.
__global__ void aggregate(const _Float16* __restrict__ propD, const _Float16* __restrict__ gate,
                          const unsigned* __restrict__ packed,
                          const int* __restrict__ endoff,
                          int dh, float* __restrict__ out)
{
    int tgt  = blockIdx.x * 4 + (threadIdx.x >> 6);
    int lane = threadIdx.x & 63;

    int st[8], P[9];
    P[0] = 0;
    #pragma unroll
    for (int c = 0; c < 8; ++c){
        int lin = c * N_NODES + tgt;
        int a1 = endoff[lin];
        int a0 = lin ? endoff[lin - 1] : 0;
        st[c] = a0;
        P[c + 1] = P[c] + (a1 - a0);
    }
    int n = P[8];

    const _Float16* pbase = propD + (size_t)dh * NTYPES * M_PAD * 128;
    const _Float16* gbase = gate + dh * 128;

    float a00 = 0.f, a01 = 0.f, a10 = 0.f, a11 = 0.f;

    for (int c0 = 0; c0 < n; c0 += 64){
        int e = c0 + lane;
        int idx = st[0] + e;
        #pragma unroll
        for (int c = 1; c < 8; ++c)
            if (e >= P[c]) idx = st[c] + (e - P[c]);
        unsigned wv = (e < n) ? packed[idx] : 0u;
        int m = n - c0; if (m > 64) m = 64;
        int e2 = 0;
        for (; e2 + 1 < m; e2 += 2){
            unsigned w0 = (unsigned)__builtin_amdgcn_readlane((int)wv, e2);
            unsigned w1 = (unsigned)__builtin_amdgcn_readlane((int)wv, e2 + 1);
            int src0 = (int)(w0 & 0x1FFFFu);
            int pz0  = (int)((w0 >> 17) & 0x1FFu);
            int ty0  = (int)(w0 >> 26);
            int src1 = (int)(w1 & 0x1FFFFu);
            int pz1  = (int)((w1 >> 17) & 0x1FFu);
            int ty1  = (int)(w1 >> 26);
            const _Float16* p0 = pbase + ((size_t)ty0 * M_PAD + (size_t)src0) * 128;
            const _Float16* g0 = gbase + (size_t)pz0 * 256;
            const _Float16* p1 = pbase + ((size_t)ty1 * M_PAD + (size_t)src1) * 128;
            const _Float16* g1 = gbase + (size_t)pz1 * 256;
            f16x2 pv0 = *(const f16x2*)(p0 + lane * 2);
            f16x2 gv0 = *(const f16x2*)(g0 + lane * 2);
            f16x2 pv1 = *(const f16x2*)(p1 + lane * 2);
            f16x2 gv1 = *(const f16x2*)(g1 + lane * 2);
            a00 += (float)pv0[0] * (float)gv0[0];
            a01 += (float)pv0[1] * (float)gv0[1];
            a10 += (float)pv1[0] * (float)gv1[0];
            a11 += (float)pv1[1] * (float)gv1[1];
        }
        if (e2 < m){
            unsigned w0 = (unsigned)__builtin_amdgcn_readlane((int)wv, e2);
            int src0 = (int)(w0 & 0x1FFFFu);
            int pz0  = (int)((w0 >> 17) & 0x1FFu);
            int ty0  = (int)(w0 >> 26);
            const _Float16* p0 = pbase + ((size_t)ty0 * M_PAD + (size_t)src0) * 128;
            const _Float16* g0 = gbase + (size_t)pz0 * 256;
            f16x2 pv0 = *(const f16x2*)(p0 + lane * 2);
            f16x2 gv0 = *(const f16x2*)(g0 + lane * 2);
            a00 += (float)pv0[0] * (float)gv0[0];
            a01 += (float)pv0[1] * (float)gv0[1];
        }
    }
    a00 += a10; a01 += a11;
    float inv = ((n == 0) ? 1.0f : (float)n) + 1e-8f;
    float2 r = make_float2(a00 / inv, a01 / inv);
    *(float2*)(out + (size_t)tgt * DIM + dh * 128 + lane * 2) = r;
}

extern "C" void kernel_launch(void* const* d_in, const int* in_sizes, int n_in,
                              void* d_out, int out_size, void* d_ws, size_t ws_size,
                              hipStream_t stream)
{
    const float* x     = (const float*)d_in[0];
    const float* W     = (const float*)d_in[1];
    const float* b     = (const float*)d_in[2];
    const float* Wp    = (const float*)d_in[3];
    const float* bp    = (const float*)d_in[4];
    const int*   edges = (const int*)d_in[5];
    const int*   posl  = (const int*)d_in[6];
    float* out = (float*)d_out;

    char* ws = (char*)d_ws;
    size_t o = 0;
    auto alloc = [&](size_t bytes){ void* p = ws + o; o += (bytes + 255) & ~(size_t)255; return p; };

    _Float16* propD = (_Float16*)alloc((size_t)2 * NTYPES * M_PAD * 128 * 2);  // 307.5 MB
    _Float16* Bp    = (_Float16*)alloc((size_t)NTYPES * 256 * 256 * 2);
    _Float16* gate  = (_Float16*)alloc((size_t)512 * 256 * 2);
    int*      buf   = (int*)alloc((size_t)NSCAN * 4);          // cnt->offs->ends
    unsigned* packed= (unsigned*)alloc((size_t)TOTAL_E * 4);
    int*      bsum  = (int*)alloc((size_t)SCAN_BLKS * 4 + 256);
    int*      ssum  = (int*)alloc((size_t)SCAN_BLKS * 4 + 256);

    hipMemsetAsync(buf, 0, (size_t)NSCAN * 4, stream);

    build_b16<<<192, 256, 0, stream>>>(W, Bp);
    build_gating<<<512, 256, 0, stream>>>(Wp, bp, gate);
    hist_kernel<<<2344, 256, 0, stream>>>(edges, buf);
    scan1_kernel<<<SCAN_BLKS, 256, 0, stream>>>(buf, bsum);
    scan2_kernel<<<1, 256, 0, stream>>>(bsum, ssum);
    scan3_kernel<<<3125, 256, 0, stream>>>(buf, ssum);
    scatter_kernel<<<2344, 256, 0, stream>>>(edges, posl, buf, packed);

    gemm_f16<<<2346, 512, 0, stream>>>(x, Bp,                 b,       propD, 0);
    gemm_f16<<<2346, 512, 0, stream>>>(x, Bp + 3 * 256 * 256, b + 768, propD, 3);

    aggregate<<<25000, 256, 0, stream>>>(propD, gate, packed, buf, 0, out);
    aggregate<<<25000, 256, 0, stream>>>(propD, gate, packed, buf, 1, out);
}